// Round 4
// baseline (535.271 us; speedup 1.0000x reference)
//
#include <hip/hip_runtime.h>

// DenseNet ValueModel, bf16 3-term split MFMA, v3.
// Pre-kernel splits W into hi/lo bf16 in d_ws, PRE-FRAGMENTED in the exact
// mfma_f32_32x32x16_bf16 B-operand layout (per chunk of 16 K-rows:
// [n0 hi 1KB][n0 lo 1KB][n1 hi 576B][n1 lo 576B], n1 compacted to 18 live
// j-cols). Main kernel: TR=24 rows/block; x kept as hi/lo bf16 planes in
// LDS; per 16-K chunk ONE wave (ci%8==w) loads B straight from global
// (lane-linear, coalesced, L2-hot) + A from LDS and issues 6 MFMAs
// (al*bh + ah*bl + ah*bh per n-tile). Per-layer 8-slab cross-wave
// reduction; 4 barriers/layer.

#define IN 16
#define KJ 50
#define NL 25
#define FW 1266
#define TR 24
#define NB 1366          // ceil(32768/24); last block: 8 live rows
#define BTOT 32768
#define XSTR 1288        // u16/row; 2576B row stride: 16B-aligned, 644%32==4 -> conflict-free b128
#define NTHREADS 512
#define XLO_OFF 61824    // 24*1288*2
#define SLAB_OFF 123648  // 2*61824
#define LDS_BYTES 156416 // + 32KB slab; A-row-overrun reads (rows 24..31) stay in-bounds
#define CHUNK_STRIDE 3200   // d_ws bytes/chunk: 2*1024 (n0 hi/lo) + 2*576 (n1 hi/lo, 18 j)
#define TOTAL_CHUNKS 973    // sum_{i<25} ceil((16+50i)/16)

typedef __attribute__((ext_vector_type(8))) short bf16x8;
typedef __attribute__((ext_vector_type(16))) float f32x16;

__device__ __forceinline__ unsigned short bf16_hi(float x, float* hif) {
    unsigned u = __float_as_uint(x);
    unsigned h = (u + 0x8000u) >> 16;
    *hif = __uint_as_float(h << 16);
    return (unsigned short)h;
}
__device__ __forceinline__ unsigned short bf16_rnd(float x) {
    return (unsigned short)((__float_as_uint(x) + 0x8000u) >> 16);
}

// ---------------- pre-kernel: split + fragment W into d_ws ----------------
__device__ __forceinline__ void split8(const float* __restrict__ rowp, int kb, int width,
                                       unsigned hi[4], unsigned lo[4]) {
#pragma unroll
    for (int p = 0; p < 4; ++p) {
        unsigned h2[2], l2[2];
#pragma unroll
        for (int q = 0; q < 2; ++q) {
            int k = kb + p * 2 + q;
            float v = (k < width) ? rowp[k] : 0.f;
            float hif;
            unsigned short h = bf16_hi(v, &hif);
            h2[q] = h;
            l2[q] = bf16_rnd(v - hif);
        }
        hi[p] = h2[0] | (h2[1] << 16);
        lo[p] = l2[0] | (l2[1] << 16);
    }
}

__global__ __launch_bounds__(64, 1) void split_w(const float* __restrict__ Ws,
                                                 char* __restrict__ wsbuf) {
    int rem = blockIdx.x, layer = 0;
    size_t off = 0;
    for (;;) {
        int c = (IN + KJ * layer + 15) >> 4;
        if (rem < c) break;
        rem -= c; off += (size_t)c * CHUNK_STRIDE; ++layer;
    }
    const int ci = rem, k0 = ci << 4, width = IN + KJ * layer;
    const float* Wl = Ws + (size_t)layer * KJ * FW;
    char* base = wsbuf + off + (size_t)ci * CHUNK_STRIDE;
    const int l = threadIdx.x, ll = l & 31, kh = l >> 5;
    const int kb = k0 + kh * 8;

    unsigned hi[4], lo[4];
    split8(Wl + (size_t)ll * FW, kb, width, hi, lo);          // n0: j = ll (< 50)
    *reinterpret_cast<uint4*>(base + l * 16)        = make_uint4(hi[0], hi[1], hi[2], hi[3]);
    *reinterpret_cast<uint4*>(base + 1024 + l * 16) = make_uint4(lo[0], lo[1], lo[2], lo[3]);
    if (ll < 18) {                                            // n1: j = 32+ll (<= 49), compacted
        split8(Wl + (size_t)(32 + ll) * FW, kb, width, hi, lo);
        *reinterpret_cast<uint4*>(base + 2048 + (kh * 18 + ll) * 16) = make_uint4(hi[0], hi[1], hi[2], hi[3]);
        *reinterpret_cast<uint4*>(base + 2624 + (kh * 18 + ll) * 16) = make_uint4(lo[0], lo[1], lo[2], lo[3]);
    }
}

// ---------------- main kernel ----------------
__global__ __launch_bounds__(NTHREADS, 1) void densenet_mfma(
    const float* __restrict__ state, const char* __restrict__ wsbuf,
    const float* __restrict__ bs,    const float* __restrict__ Wout,
    const float* __restrict__ bout,  float* __restrict__ out)
{
    __shared__ __align__(16) char lds[LDS_BYTES];
    unsigned short* xhi = (unsigned short*)lds;
    unsigned short* xlo = (unsigned short*)(lds + XLO_OFF);
    float* slab = (float*)(lds + SLAB_OFF);

    const int tid = threadIdx.x;
    const int w   = tid >> 6;
    const int l   = tid & 63;
    const int ll  = l & 31, kh = l >> 5;
    const long row0 = (long)blockIdx.x * TR;

    // zero x planes (zero padding masks k-tails; rows beyond live batch stay 0)
    {
        unsigned* p = (unsigned*)lds;
        for (int i = tid; i < (XLO_OFF * 2) / 4; i += NTHREADS) p[i] = 0u;
    }
    __syncthreads();
    if (tid < TR * IN) {
        int r = tid >> 4, c = tid & 15;
        if (row0 + r < BTOT) {
            float v = state[(row0 + r) * IN + c];
            float hif;
            xhi[r * XSTR + c] = bf16_hi(v, &hif);
            xlo[r * XSTR + c] = bf16_rnd(v - hif);
        }
    }

    int width = IN;
    size_t wofs = 0;
    for (int layer = 0; layer < NL; ++layer) {
        const int chunks = (width + 15) >> 4;
        f32x16 acc0, acc1;
#pragma unroll
        for (int i = 0; i < 16; ++i) { acc0[i] = 0.f; acc1[i] = 0.f; }

        __syncthreads();   // (A) x writes + prev slab reads complete

        const char* wb = wsbuf + wofs;
        for (int ci = w; ci < chunks; ci += 8) {        // wave-owned K-chunks
            const char* cb = wb + (size_t)ci * CHUNK_STRIDE;
            const int kof = (ci << 4) + (kh << 3);
            bf16x8 ah = *(const bf16x8*)&xhi[ll * XSTR + kof];   // rows 24..31: in-bounds garbage,
            bf16x8 al = *(const bf16x8*)&xlo[ll * XSTR + kof];   // confined to dead acc regs 12..15
            bf16x8 bh0 = *(const bf16x8*)(cb + l * 16);
            bf16x8 bl0 = *(const bf16x8*)(cb + 1024 + l * 16);
            bf16x8 bh1 = {0,0,0,0,0,0,0,0}, bl1 = {0,0,0,0,0,0,0,0};
            if (ll < 18) {
                bh1 = *(const bf16x8*)(cb + 2048 + (kh * 18 + ll) * 16);
                bl1 = *(const bf16x8*)(cb + 2624 + (kh * 18 + ll) * 16);
            }
            acc0 = __builtin_amdgcn_mfma_f32_32x32x16_bf16(al, bh0, acc0, 0, 0, 0);
            acc0 = __builtin_amdgcn_mfma_f32_32x32x16_bf16(ah, bl0, acc0, 0, 0, 0);
            acc0 = __builtin_amdgcn_mfma_f32_32x32x16_bf16(ah, bh0, acc0, 0, 0, 0);
            acc1 = __builtin_amdgcn_mfma_f32_32x32x16_bf16(al, bh1, acc1, 0, 0, 0);
            acc1 = __builtin_amdgcn_mfma_f32_32x32x16_bf16(ah, bl1, acc1, 0, 0, 0);
            acc1 = __builtin_amdgcn_mfma_f32_32x32x16_bf16(ah, bh1, acc1, 0, 0, 0);
        }

        // half 1: C rows 0..15 <-> acc regs 0..7  (C: col=l&31, row=(r&3)+8*(r>>2)+4*(l>>5))
#pragma unroll
        for (int r = 0; r < 8; ++r) {
            slab[w * 1024 + (0 * 8 + r) * 64 + l] = acc0[r];
            slab[w * 1024 + (1 * 8 + r) * 64 + l] = acc1[r];
        }
        __syncthreads();   // (B) slab h1 written; all A-reads done -> x writable
        for (int idx = tid; idx < 16 * KJ; idx += NTHREADS) {
            int row = idx / KJ, j = idx % KJ;
            int n = j >> 5;
            int lj = (j & 31) | (((row >> 2) & 1) << 5);
            int r = (row & 3) | ((row >> 3) << 2);
            float s = 0.f;
#pragma unroll
            for (int q = 0; q < 8; ++q) s += slab[q * 1024 + (n * 8 + r) * 64 + lj];
            s += bs[layer * KJ + j];
            s = (s > 0.f) ? s : 0.01f * s;
            float hif;
            xhi[row * XSTR + width + j] = bf16_hi(s, &hif);
            xlo[row * XSTR + width + j] = bf16_rnd(s - hif);
        }
        __syncthreads();   // (C) slab h1 reads done
        // half 2: C rows 16..23 <-> acc regs 8..11
#pragma unroll
        for (int r = 0; r < 4; ++r) {
            slab[w * 512 + (0 * 4 + r) * 64 + l] = acc0[8 + r];
            slab[w * 512 + (1 * 4 + r) * 64 + l] = acc1[8 + r];
        }
        __syncthreads();   // (D)
        for (int idx = tid; idx < 8 * KJ; idx += NTHREADS) {
            int row = idx / KJ + 16, j = idx % KJ;
            int n = j >> 5;
            int lj = (j & 31) | (((row >> 2) & 1) << 5);
            int r = row & 3;
            float s = 0.f;
#pragma unroll
            for (int q = 0; q < 8; ++q) s += slab[q * 512 + (n * 4 + r) * 64 + lj];
            s += bs[layer * KJ + j];
            s = (s > 0.f) ? s : 0.01f * s;
            float hif;
            xhi[row * XSTR + width + j] = bf16_hi(s, &hif);
            xlo[row * XSTR + width + j] = bf16_rnd(s - hif);
        }
        width += KJ;
        wofs += (size_t)chunks * CHUNK_STRIDE;
    }

    __syncthreads();   // x (width 1266) complete
    // epilogue: out[r] = x[r] . Wout + bout ; 3 rows/wave, 64-lane dot
#pragma unroll
    for (int rr = 0; rr < 3; ++rr) {
        const int row = w * 3 + rr;
        const long grow = row0 + row;
        float s = 0.f;
        for (int k = l; k < FW; k += 64) {
            float xv = __uint_as_float((unsigned)xhi[row * XSTR + k] << 16)
                     + __uint_as_float((unsigned)xlo[row * XSTR + k] << 16);
            s += xv * Wout[k];
        }
#pragma unroll
        for (int m = 32; m >= 1; m >>= 1) s += __shfl_xor(s, m, 64);
        if (l == 0 && grow < BTOT) out[grow] = s + bout[0];
    }
}

extern "C" void kernel_launch(void* const* d_in, const int* in_sizes, int n_in,
                              void* d_out, int out_size, void* d_ws, size_t ws_size,
                              hipStream_t stream) {
    const float* state = (const float*)d_in[0];
    const float* Ws    = (const float*)d_in[1];
    const float* bs    = (const float*)d_in[2];
    const float* Wout  = (const float*)d_in[3];
    const float* bout  = (const float*)d_in[4];
    float* out = (float*)d_out;
    char* wsbuf = (char*)d_ws;   // needs TOTAL_CHUNKS*CHUNK_STRIDE = 3,113,600 B

    split_w<<<dim3(TOTAL_CHUNKS), dim3(64), 0, stream>>>(Ws, wsbuf);
    densenet_mfma<<<dim3(NB), dim3(NTHREADS), 0, stream>>>(state, wsbuf, bs, Wout, bout, out);
}